// Round 3
// baseline (147.511 us; speedup 1.0000x reference)
//
#include <hip/hip_runtime.h>
#include <math.h>

#define BB 32
#define SS 4096
#define DIN 1024
#define DOUT 1024
#define NCHUNK 32                          // s-chunks per batch row
#define ROWS_PER_BLOCK (SS / NCHUNK)       // 128
#define ROWS_PER_WAVE (ROWS_PER_BLOCK / 4) // 32
#define PART_STRIDE 1040                   // floats: [0]=m, [1]=l, [16..1039]=ctx[1024]

typedef float vf4 __attribute__((ext_vector_type(4)));

// ---------------- kernel 1: x[b,o] = sum_i input[b,i] * W[o,i] ----------------
// 256 blocks; block oc owns o-rows oc*4..oc*4+3 (one per wave), loops over b.
// W is read from HBM exactly once (4 MB total).
__global__ __launch_bounds__(256) void proj_kernel(const float* __restrict__ input,
                                                   const float* __restrict__ W,
                                                   float* __restrict__ x) {
  const int oc = blockIdx.x;
  const int t = threadIdx.x, wave = t >> 6, lane = t & 63;
  const int o = oc * 4 + wave;

  vf4 wv[4];
  const vf4* wrow = (const vf4*)(W + (size_t)o * DIN);
#pragma unroll
  for (int k = 0; k < 4; ++k) wv[k] = wrow[lane + 64 * k];

  __shared__ float inp[DIN];
  for (int b = 0; b < BB; ++b) {
    __syncthreads();
    ((vf4*)inp)[t] = ((const vf4*)(input + (size_t)b * DIN))[t];  // 256 lanes x 16B = 4KB
    __syncthreads();
    vf4 prod = (vf4)0.f;
#pragma unroll
    for (int k = 0; k < 4; ++k) prod += wv[k] * ((const vf4*)inp)[lane + 64 * k];
    float dot = prod.x + prod.y + prod.z + prod.w;
#pragma unroll
    for (int off = 32; off; off >>= 1) dot += __shfl_xor(dot, off);
    if (lane == 0) x[(size_t)b * DOUT + o] = dot;
  }
}

// ---- kernel 2: single pass over source_hids: scores + online softmax + ctx ----
__global__ __launch_bounds__(256) void pass_kernel(const float* __restrict__ hids,
                                                   const float* __restrict__ seg,
                                                   const float* __restrict__ x,
                                                   float* __restrict__ raw_scores,   // d_out attn region
                                                   float* __restrict__ partials) {
  const int b = blockIdx.x >> 5;        // 32 chunks per b
  const int chunk = blockIdx.x & 31;
  const int t = threadIdx.x;
  __shared__ float xs[DOUT];
  __shared__ float buf[4][DOUT];
  __shared__ float sbuf[ROWS_PER_BLOCK];
  __shared__ float wstat[8];            // m[0..3], l[4..7]
  ((float4*)xs)[t] = ((const float4*)(x + (size_t)b * DOUT))[t];
  __syncthreads();
  const int wave = t >> 6, lane = t & 63;
  vf4 xv[4];
#pragma unroll
  for (int k = 0; k < 4; ++k) xv[k] = ((const vf4*)xs)[lane + 64 * k];

  const int s0 = chunk * ROWS_PER_BLOCK + wave * ROWS_PER_WAVE;
  const float* base = hids + ((size_t)b * SS + s0) * (size_t)DOUT;
  const float* segb = seg + (size_t)b * SS + s0;

  float m = -INFINITY, l = 0.f;
  vf4 acc[4];
#pragma unroll
  for (int k = 0; k < 4; ++k) acc[k] = (vf4)0.f;

  // depth-1 register prefetch pipeline over the 32 rows this wave owns
  vf4 h[4];
#pragma unroll
  for (int k = 0; k < 4; ++k) h[k] = ((const vf4*)base)[lane + 64 * k];

#pragma unroll 4
  for (int r = 0; r < ROWS_PER_WAVE; ++r) {
    vf4 hn[4];
    if (r + 1 < ROWS_PER_WAVE) {
      const vf4* nb = (const vf4*)(base + (size_t)(r + 1) * DOUT);
#pragma unroll
      for (int k = 0; k < 4; ++k) hn[k] = nb[lane + 64 * k];
    }

    vf4 prod = h[0] * xv[0] + h[1] * xv[1] + h[2] * xv[2] + h[3] * xv[3];
    float dot = prod.x + prod.y + prod.z + prod.w;
#pragma unroll
    for (int off = 32; off; off >>= 1) dot += __shfl_xor(dot, off);

    const float score = dot - 100.f * (1.f - segb[r]);
    if (lane == 0) sbuf[wave * ROWS_PER_WAVE + r] = score;

    const float mnew = fmaxf(m, score);
    const float corr = __expf(m - mnew);   // first iter: exp(-inf) = 0
    const float p = __expf(score - mnew);
    l = l * corr + p;
#pragma unroll
    for (int k = 0; k < 4; ++k) acc[k] = acc[k] * corr + p * h[k];
    m = mnew;
#pragma unroll
    for (int k = 0; k < 4; ++k) h[k] = hn[k];
  }

  // ---- block-level combine of the 4 waves ----
  if (lane == 0) { wstat[wave] = m; wstat[4 + wave] = l; }
  __syncthreads();
  const float mb = fmaxf(fmaxf(wstat[0], wstat[1]), fmaxf(wstat[2], wstat[3]));
  const float scale = __expf(m - mb);     // per-wave scale
#pragma unroll
  for (int k = 0; k < 4; ++k)
    ((vf4*)buf[wave])[lane + 64 * k] = acc[k] * scale;
  __syncthreads();

  // coalesced raw-score write (one block: 128 contiguous floats)
  if (t < ROWS_PER_BLOCK)
    raw_scores[(size_t)b * SS + chunk * ROWS_PER_BLOCK + t] = sbuf[t];

  float* part = partials + ((size_t)b * NCHUNK + chunk) * PART_STRIDE;
  vf4 v0 = ((const vf4*)buf[0])[t];
  vf4 v1 = ((const vf4*)buf[1])[t];
  vf4 v2 = ((const vf4*)buf[2])[t];
  vf4 v3 = ((const vf4*)buf[3])[t];
  ((vf4*)(part + 16))[t] = (v0 + v1) + (v2 + v3);
  if (t == 0) {
    const float lb = wstat[4] * __expf(wstat[0] - mb) + wstat[5] * __expf(wstat[1] - mb) +
                     wstat[6] * __expf(wstat[2] - mb) + wstat[7] * __expf(wstat[3] - mb);
    part[0] = mb;
    part[1] = lb;
  }
}

// ---- kernel 3: merge partials -> ctx out; normalize attn. 8 blocks per b ----
__global__ __launch_bounds__(128) void combine_kernel(const float* __restrict__ partials,
                                                      float* __restrict__ out_ctx,
                                                      float* __restrict__ out_attn) {
  const int b = blockIdx.x >> 3;
  const int part = blockIdx.x & 7;
  const int t = threadIdx.x;            // 0..127
  const float* pb = partials + (size_t)b * NCHUNK * PART_STRIDE;

  __shared__ float sm[NCHUNK], sl[NCHUNK];
  if (t < NCHUNK) {
    sm[t] = pb[(size_t)t * PART_STRIDE];
    sl[t] = pb[(size_t)t * PART_STRIDE + 1];
  }
  __syncthreads();

  float m = -INFINITY;
#pragma unroll
  for (int j = 0; j < NCHUNK; ++j) m = fmaxf(m, sm[j]);
  float l = 0.f;
#pragma unroll
  for (int j = 0; j < NCHUNK; ++j) l += sl[j] * __expf(sm[j] - m);
  const float inv_l = 1.f / l;

  // this block's 128 ctx elements
  float c = 0.f;
#pragma unroll 8
  for (int j = 0; j < NCHUNK; ++j)
    c += __expf(sm[j] - m) * pb[(size_t)j * PART_STRIDE + 16 + part * 128 + t];
  out_ctx[(size_t)b * DOUT + part * 128 + t] = c * inv_l;

  // this block's 512 attn scores (as 128 float4)
  float* arow = out_attn + (size_t)b * SS + part * 512;
  float4 v = ((float4*)arow)[t];
  v.x = __expf(v.x - m) * inv_l;
  v.y = __expf(v.y - m) * inv_l;
  v.z = __expf(v.z - m) * inv_l;
  v.w = __expf(v.w - m) * inv_l;
  ((float4*)arow)[t] = v;
}

extern "C" void kernel_launch(void* const* d_in, const int* in_sizes, int n_in,
                              void* d_out, int out_size, void* d_ws, size_t ws_size,
                              hipStream_t stream) {
  const float* input = (const float*)d_in[0];   // [B, DIN]
  const float* hids  = (const float*)d_in[1];   // [B, S, DOUT]
  const float* seg   = (const float*)d_in[2];   // [B, S]
  const float* W     = (const float*)d_in[3];   // [DOUT, DIN]
  float* out = (float*)d_out;
  float* out_ctx  = out;                        // [B, DOUT]
  float* out_attn = out + (size_t)BB * DOUT;    // [B, S]

  float* x        = (float*)d_ws;               // [B, DOUT]
  float* partials = x + (size_t)BB * DOUT;      // [B, NCHUNK, PART_STRIDE]

  proj_kernel<<<DOUT / 4, 256, 0, stream>>>(input, W, x);
  pass_kernel<<<BB * NCHUNK, 256, 0, stream>>>(hids, seg, x, out_attn, partials);
  combine_kernel<<<BB * 8, 128, 0, stream>>>(partials, out_ctx, out_attn);
}

// Round 4
// 126.547 us; speedup vs baseline: 1.1657x; 1.1657x over previous
//
#include <hip/hip_runtime.h>
#include <math.h>

#define BB 32
#define SS 4096
#define DIN 1024
#define DOUT 1024
#define NCHUNK 32                          // s-chunks per batch row
#define ROWS_PER_BLOCK (SS / NCHUNK)       // 128
#define ROWS_PER_WAVE (ROWS_PER_BLOCK / 4) // 32
#define PART_STRIDE 1040                   // floats: [0]=m, [1]=l, [16..1039]=ctx[1024]

typedef float vf4 __attribute__((ext_vector_type(4)));

__device__ inline vf4 ntload4(const float* p) {
  return __builtin_nontemporal_load((const vf4*)p);
}

// ---------------- kernel 1: x[b,o] = sum_i input[b,i] * W[o,i] ----------------
// 256 blocks; block oc owns o-rows oc*4..oc*4+3 (one per wave), loops over b.
// W is read from HBM exactly once (4 MB total).
__global__ __launch_bounds__(256) void proj_kernel(const float* __restrict__ input,
                                                   const float* __restrict__ W,
                                                   float* __restrict__ x) {
  const int oc = blockIdx.x;
  const int t = threadIdx.x, wave = t >> 6, lane = t & 63;
  const int o = oc * 4 + wave;

  vf4 wv[4];
  const float* wrow = W + (size_t)o * DIN;
#pragma unroll
  for (int k = 0; k < 4; ++k) wv[k] = ntload4(wrow + (lane + 64 * k) * 4);

  __shared__ float inp[DIN];
  for (int b = 0; b < BB; ++b) {
    __syncthreads();
    ((vf4*)inp)[t] = ((const vf4*)(input + (size_t)b * DIN))[t];  // 256 lanes x 16B = 4KB
    __syncthreads();
    vf4 prod = (vf4)0.f;
#pragma unroll
    for (int k = 0; k < 4; ++k) prod += wv[k] * ((const vf4*)inp)[lane + 64 * k];
    float dot = prod.x + prod.y + prod.z + prod.w;
#pragma unroll
    for (int off = 32; off; off >>= 1) dot += __shfl_xor(dot, off);
    if (lane == 0) x[(size_t)b * DOUT + o] = dot;
  }
}

// ---- kernel 2: single pass over source_hids: scores + online softmax + ctx ----
__global__ __launch_bounds__(256) void pass_kernel(const float* __restrict__ hids,
                                                   const float* __restrict__ seg,
                                                   const float* __restrict__ x,
                                                   float* __restrict__ raw_scores,   // d_out attn region
                                                   float* __restrict__ partials) {
  const int b = blockIdx.x >> 5;        // 32 chunks per b
  const int chunk = blockIdx.x & 31;
  const int t = threadIdx.x;
  __shared__ float xs[DOUT];
  __shared__ float buf[4][DOUT];
  __shared__ float sbuf[ROWS_PER_BLOCK];
  __shared__ float wstat[8];            // m[0..3], l[4..7]
  ((float4*)xs)[t] = ((const float4*)(x + (size_t)b * DOUT))[t];
  __syncthreads();
  const int wave = t >> 6, lane = t & 63;
  vf4 xv[4];
#pragma unroll
  for (int k = 0; k < 4; ++k) xv[k] = ((const vf4*)xs)[lane + 64 * k];

  const int s0 = chunk * ROWS_PER_BLOCK + wave * ROWS_PER_WAVE;
  const float* base = hids + ((size_t)b * SS + s0) * (size_t)DOUT;
  const float* segb = seg + (size_t)b * SS + s0;

  // all 32 seg values for this wave in one coalesced load (lane&31 avoids OOB)
  const float segv = segb[lane & 31];

  float m = -INFINITY, l = 0.f;
  vf4 acc[4];
#pragma unroll
  for (int k = 0; k < 4; ++k) acc[k] = (vf4)0.f;

  // depth-1 register prefetch pipeline over the 32 rows this wave owns
  vf4 h[4];
#pragma unroll
  for (int k = 0; k < 4; ++k) h[k] = ntload4(base + (lane + 64 * k) * 4);

#pragma unroll 4
  for (int r = 0; r < ROWS_PER_WAVE; ++r) {
    vf4 hn[4];
    if (r + 1 < ROWS_PER_WAVE) {
      const float* nb = base + (size_t)(r + 1) * DOUT;
#pragma unroll
      for (int k = 0; k < 4; ++k) hn[k] = ntload4(nb + (lane + 64 * k) * 4);
    }

    vf4 prod = h[0] * xv[0] + h[1] * xv[1] + h[2] * xv[2] + h[3] * xv[3];
    float dot = prod.x + prod.y + prod.z + prod.w;
#pragma unroll
    for (int off = 32; off; off >>= 1) dot += __shfl_xor(dot, off);

    const float score = dot - 100.f * (1.f - __shfl(segv, r));
    if (lane == 0) sbuf[wave * ROWS_PER_WAVE + r] = score;

    const float mnew = fmaxf(m, score);
    const float corr = __expf(m - mnew);   // first iter: exp(-inf) = 0
    const float p = __expf(score - mnew);
    l = l * corr + p;
#pragma unroll
    for (int k = 0; k < 4; ++k) acc[k] = acc[k] * corr + p * h[k];
    m = mnew;
#pragma unroll
    for (int k = 0; k < 4; ++k) h[k] = hn[k];
  }

  // ---- block-level combine of the 4 waves ----
  if (lane == 0) { wstat[wave] = m; wstat[4 + wave] = l; }
  __syncthreads();
  const float mb = fmaxf(fmaxf(wstat[0], wstat[1]), fmaxf(wstat[2], wstat[3]));
  const float scale = __expf(m - mb);     // per-wave scale
#pragma unroll
  for (int k = 0; k < 4; ++k)
    ((vf4*)buf[wave])[lane + 64 * k] = acc[k] * scale;
  __syncthreads();

  // coalesced raw-score write (one block: 128 contiguous floats)
  if (t < ROWS_PER_BLOCK)
    raw_scores[(size_t)b * SS + chunk * ROWS_PER_BLOCK + t] = sbuf[t];

  float* part = partials + ((size_t)b * NCHUNK + chunk) * PART_STRIDE;
  vf4 v0 = ((const vf4*)buf[0])[t];
  vf4 v1 = ((const vf4*)buf[1])[t];
  vf4 v2 = ((const vf4*)buf[2])[t];
  vf4 v3 = ((const vf4*)buf[3])[t];
  ((vf4*)(part + 16))[t] = (v0 + v1) + (v2 + v3);
  if (t == 0) {
    const float lb = wstat[4] * __expf(wstat[0] - mb) + wstat[5] * __expf(wstat[1] - mb) +
                     wstat[6] * __expf(wstat[2] - mb) + wstat[7] * __expf(wstat[3] - mb);
    part[0] = mb;
    part[1] = lb;
  }
}

// ---- kernel 3: merge partials -> ctx out; normalize attn. 8 blocks per b ----
__global__ __launch_bounds__(128) void combine_kernel(const float* __restrict__ partials,
                                                      float* __restrict__ out_ctx,
                                                      float* __restrict__ out_attn) {
  const int b = blockIdx.x >> 3;
  const int part = blockIdx.x & 7;
  const int t = threadIdx.x;            // 0..127
  const float* pb = partials + (size_t)b * NCHUNK * PART_STRIDE;

  __shared__ float sm[NCHUNK], sl[NCHUNK];
  if (t < NCHUNK) {
    sm[t] = pb[(size_t)t * PART_STRIDE];
    sl[t] = pb[(size_t)t * PART_STRIDE + 1];
  }
  __syncthreads();

  float m = -INFINITY;
#pragma unroll
  for (int j = 0; j < NCHUNK; ++j) m = fmaxf(m, sm[j]);
  float l = 0.f;
#pragma unroll
  for (int j = 0; j < NCHUNK; ++j) l += sl[j] * __expf(sm[j] - m);
  const float inv_l = 1.f / l;

  // this block's 128 ctx elements
  float c = 0.f;
#pragma unroll 8
  for (int j = 0; j < NCHUNK; ++j)
    c += __expf(sm[j] - m) * pb[(size_t)j * PART_STRIDE + 16 + part * 128 + t];
  out_ctx[(size_t)b * DOUT + part * 128 + t] = c * inv_l;

  // this block's 512 attn scores (as 128 float4)
  float* arow = out_attn + (size_t)b * SS + part * 512;
  float4 v = ((float4*)arow)[t];
  v.x = __expf(v.x - m) * inv_l;
  v.y = __expf(v.y - m) * inv_l;
  v.z = __expf(v.z - m) * inv_l;
  v.w = __expf(v.w - m) * inv_l;
  ((float4*)arow)[t] = v;
}

extern "C" void kernel_launch(void* const* d_in, const int* in_sizes, int n_in,
                              void* d_out, int out_size, void* d_ws, size_t ws_size,
                              hipStream_t stream) {
  const float* input = (const float*)d_in[0];   // [B, DIN]
  const float* hids  = (const float*)d_in[1];   // [B, S, DOUT]
  const float* seg   = (const float*)d_in[2];   // [B, S]
  const float* W     = (const float*)d_in[3];   // [DOUT, DIN]
  float* out = (float*)d_out;
  float* out_ctx  = out;                        // [B, DOUT]
  float* out_attn = out + (size_t)BB * DOUT;    // [B, S]

  float* x        = (float*)d_ws;               // [B, DOUT]
  float* partials = x + (size_t)BB * DOUT;      // [B, NCHUNK, PART_STRIDE]

  proj_kernel<<<DOUT / 4, 256, 0, stream>>>(input, W, x);
  pass_kernel<<<BB * NCHUNK, 256, 0, stream>>>(hids, seg, x, out_attn, partials);
  combine_kernel<<<BB * 8, 128, 0, stream>>>(partials, out_ctx, out_attn);
}

// Round 5
// 104.135 us; speedup vs baseline: 1.4165x; 1.2152x over previous
//
#include <hip/hip_runtime.h>
#include <math.h>

#define BB 32
#define SS 4096
#define DIN 1024
#define DOUT 1024
#define NCHUNK 32                          // s-chunks per batch row
#define ROWS_PER_BLOCK (SS / NCHUNK)       // 128
#define ROWS_PER_WAVE (ROWS_PER_BLOCK / 4) // 32
#define PART_STRIDE 1040                   // floats: [0]=m, [1]=l, [16..1039]=ctx[1024]
#define THR 25.0f                          // defer-max rescale threshold (e^25 safe in f32)

typedef float vf4 __attribute__((ext_vector_type(4)));

__device__ inline vf4 ntload4(const float* p) {
  return __builtin_nontemporal_load((const vf4*)p);
}

// ---------------- kernel 1: x[b,o] = sum_i input[b,i] * W[o,i] ----------------
// R2 form: 1024 blocks (b, ochunk), 8 o-dots per wave, fully parallel.
__global__ __launch_bounds__(256) void proj_kernel(const float* __restrict__ input,
                                                   const float* __restrict__ W,
                                                   float* __restrict__ x) {
  const int b = blockIdx.x >> 5;        // 32 o-chunks per b
  const int ochunk = blockIdx.x & 31;
  __shared__ float inp[DIN];
  const int t = threadIdx.x;
  ((vf4*)inp)[t] = ((const vf4*)(input + (size_t)b * DIN))[t];
  __syncthreads();
  const int wave = t >> 6, lane = t & 63;
#pragma unroll
  for (int j = 0; j < 8; ++j) {
    const int o = ochunk * 32 + wave * 8 + j;
    const vf4* wrow = (const vf4*)(W + (size_t)o * DIN);
    vf4 prod = (vf4)0.f;
#pragma unroll
    for (int k = 0; k < 4; ++k) prod += wrow[lane + 64 * k] * ((const vf4*)inp)[lane + 64 * k];
    float sum = prod.x + prod.y + prod.z + prod.w;
#pragma unroll
    for (int off = 32; off; off >>= 1) sum += __shfl_down(sum, off);
    if (lane == 0) x[(size_t)b * DOUT + o] = sum;
  }
}

// ---- kernel 2: single pass over source_hids: scores + online softmax + ctx ----
__global__ __launch_bounds__(256) void pass_kernel(const float* __restrict__ hids,
                                                   const float* __restrict__ seg,
                                                   const float* __restrict__ x,
                                                   float* __restrict__ raw_scores,   // d_out attn region
                                                   float* __restrict__ partials) {
  const int b = blockIdx.x >> 5;        // 32 chunks per b
  const int chunk = blockIdx.x & 31;
  const int t = threadIdx.x;
  __shared__ float xs[DOUT];
  __shared__ float buf[4][DOUT];
  __shared__ float sbuf[ROWS_PER_BLOCK];
  __shared__ float wstat[8];            // M[0..3], l[4..7]
  ((vf4*)xs)[t] = ((const vf4*)(x + (size_t)b * DOUT))[t];
  __syncthreads();
  const int wave = t >> 6, lane = t & 63;
  vf4 xv[4];
#pragma unroll
  for (int k = 0; k < 4; ++k) xv[k] = ((const vf4*)xs)[lane + 64 * k];

  const int s0 = chunk * ROWS_PER_BLOCK + wave * ROWS_PER_WAVE;
  const float* base = hids + ((size_t)b * SS + s0) * (size_t)DOUT;
  const float* segb = seg + (size_t)b * SS + s0;

  // all 32 seg values for this wave in one coalesced load (lane&31 avoids OOB)
  const float segv = segb[lane & 31];

  // ---- prologue: row 0 establishes the reference M ----
  vf4 h[4];
#pragma unroll
  for (int k = 0; k < 4; ++k) h[k] = ntload4(base + (lane + 64 * k) * 4);

  vf4 hn[4];
#pragma unroll
  for (int k = 0; k < 4; ++k) hn[k] = ntload4(base + DOUT + (lane + 64 * k) * 4);

  vf4 prod0 = h[0] * xv[0] + h[1] * xv[1] + h[2] * xv[2] + h[3] * xv[3];
  float dot0 = prod0.x + prod0.y + prod0.z + prod0.w;
#pragma unroll
  for (int off = 32; off; off >>= 1) dot0 += __shfl_xor(dot0, off);
  float M = dot0 - 100.f * (1.f - __shfl(segv, 0));
  if (lane == 0) sbuf[wave * ROWS_PER_WAVE] = M;
  float l = 1.f;
  vf4 acc[4];
#pragma unroll
  for (int k = 0; k < 4; ++k) { acc[k] = h[k]; h[k] = hn[k]; }

  // ---- main loop: rows 1..31, defer-max (rescale only when score > M+THR) ----
#pragma unroll 4
  for (int r = 1; r < ROWS_PER_WAVE; ++r) {
    if (r + 1 < ROWS_PER_WAVE) {
      const float* nb = base + (size_t)(r + 1) * DOUT;
#pragma unroll
      for (int k = 0; k < 4; ++k) hn[k] = ntload4(nb + (lane + 64 * k) * 4);
    }

    vf4 prod = h[0] * xv[0] + h[1] * xv[1] + h[2] * xv[2] + h[3] * xv[3];
    float dot = prod.x + prod.y + prod.z + prod.w;
#pragma unroll
    for (int off = 32; off; off >>= 1) dot += __shfl_xor(dot, off);

    const float score = dot - 100.f * (1.f - __shfl(segv, r));
    if (lane == 0) sbuf[wave * ROWS_PER_WAVE + r] = score;

    float p;
    if (__builtin_expect(score > M + THR, 0)) {  // wave-uniform branch, rare
      const float corr = __expf(M - score);
      l *= corr;
#pragma unroll
      for (int k = 0; k < 4; ++k) acc[k] *= corr;
      M = score;
      p = 1.f;
    } else {
      p = __expf(score - M);
    }
    l += p;
#pragma unroll
    for (int k = 0; k < 4; ++k) acc[k] += p * h[k];
#pragma unroll
    for (int k = 0; k < 4; ++k) h[k] = hn[k];
  }

  // ---- block-level combine of the 4 waves ----
  if (lane == 0) { wstat[wave] = M; wstat[4 + wave] = l; }
  __syncthreads();
  const float mb = fmaxf(fmaxf(wstat[0], wstat[1]), fmaxf(wstat[2], wstat[3]));
  const float scale = __expf(M - mb);     // per-wave scale to common reference
#pragma unroll
  for (int k = 0; k < 4; ++k)
    ((vf4*)buf[wave])[lane + 64 * k] = acc[k] * scale;
  __syncthreads();

  // coalesced raw-score write (one block: 128 contiguous floats)
  if (t < ROWS_PER_BLOCK)
    raw_scores[(size_t)b * SS + chunk * ROWS_PER_BLOCK + t] = sbuf[t];

  float* part = partials + ((size_t)b * NCHUNK + chunk) * PART_STRIDE;
  vf4 v0 = ((const vf4*)buf[0])[t];
  vf4 v1 = ((const vf4*)buf[1])[t];
  vf4 v2 = ((const vf4*)buf[2])[t];
  vf4 v3 = ((const vf4*)buf[3])[t];
  ((vf4*)(part + 16))[t] = (v0 + v1) + (v2 + v3);
  if (t == 0) {
    const float lb = wstat[4] * __expf(wstat[0] - mb) + wstat[5] * __expf(wstat[1] - mb) +
                     wstat[6] * __expf(wstat[2] - mb) + wstat[7] * __expf(wstat[3] - mb);
    part[0] = mb;
    part[1] = lb;
  }
}

// ---- kernel 3: merge partials -> ctx out; normalize attn. 8 blocks per b ----
__global__ __launch_bounds__(128) void combine_kernel(const float* __restrict__ partials,
                                                      float* __restrict__ out_ctx,
                                                      float* __restrict__ out_attn) {
  const int b = blockIdx.x >> 3;
  const int part = blockIdx.x & 7;
  const int t = threadIdx.x;            // 0..127
  const float* pb = partials + (size_t)b * NCHUNK * PART_STRIDE;

  __shared__ float sm[NCHUNK], sl[NCHUNK];
  if (t < NCHUNK) {
    sm[t] = pb[(size_t)t * PART_STRIDE];
    sl[t] = pb[(size_t)t * PART_STRIDE + 1];
  }
  __syncthreads();

  float m = -INFINITY;
#pragma unroll
  for (int j = 0; j < NCHUNK; ++j) m = fmaxf(m, sm[j]);
  float l = 0.f;
#pragma unroll
  for (int j = 0; j < NCHUNK; ++j) l += sl[j] * __expf(sm[j] - m);
  const float inv_l = 1.f / l;

  // this block's 128 ctx elements
  float c = 0.f;
#pragma unroll 8
  for (int j = 0; j < NCHUNK; ++j)
    c += __expf(sm[j] - m) * pb[(size_t)j * PART_STRIDE + 16 + part * 128 + t];
  out_ctx[(size_t)b * DOUT + part * 128 + t] = c * inv_l;

  // this block's 512 attn scores (as 128 float4)
  float* arow = out_attn + (size_t)b * SS + part * 512;
  float4 v = ((float4*)arow)[t];
  v.x = __expf(v.x - m) * inv_l;
  v.y = __expf(v.y - m) * inv_l;
  v.z = __expf(v.z - m) * inv_l;
  v.w = __expf(v.w - m) * inv_l;
  ((float4*)arow)[t] = v;
}

extern "C" void kernel_launch(void* const* d_in, const int* in_sizes, int n_in,
                              void* d_out, int out_size, void* d_ws, size_t ws_size,
                              hipStream_t stream) {
  const float* input = (const float*)d_in[0];   // [B, DIN]
  const float* hids  = (const float*)d_in[1];   // [B, S, DOUT]
  const float* seg   = (const float*)d_in[2];   // [B, S]
  const float* W     = (const float*)d_in[3];   // [DOUT, DIN]
  float* out = (float*)d_out;
  float* out_ctx  = out;                        // [B, DOUT]
  float* out_attn = out + (size_t)BB * DOUT;    // [B, S]

  float* x        = (float*)d_ws;               // [B, DOUT]
  float* partials = x + (size_t)BB * DOUT;      // [B, NCHUNK, PART_STRIDE]

  proj_kernel<<<BB * 32, 256, 0, stream>>>(input, W, x);
  pass_kernel<<<BB * NCHUNK, 256, 0, stream>>>(hids, seg, x, out_attn, partials);
  combine_kernel<<<BB * 8, 128, 0, stream>>>(partials, out_ctx, out_attn);
}